// Round 15
// baseline (617.615 us; speedup 1.0000x reference)
//
#include <hip/hip_runtime.h>
#include <hip/hip_bf16.h>

typedef __bf16 bf16_t;
typedef __attribute__((ext_vector_type(8))) __bf16 bf16x8;
typedef __attribute__((ext_vector_type(4))) float f32x4;

// ---------------- prep kernels (round-14 fast versions, verified) ----------------
__global__ __launch_bounds__(256) void prep_wvp_fast(
    const float* __restrict__ Wv, const float* __restrict__ Wp,
    const float* __restrict__ bp, const float* __restrict__ bv,
    float* __restrict__ Wvp, float* __restrict__ bvp) {
  const int t = threadIdx.x;
  const int rs = t >> 6;          // wave = row within block
  const int jg = t & 63;          // 4-col group
  const int i = blockIdx.x * 4 + rs;
  const float* wrow = Wv + (size_t)i * 512;
  float4 acc = {0.f, 0.f, 0.f, 0.f};
#pragma unroll 4
  for (int d = 0; d < 512; ++d) {
    const float s = wrow[d];
    const float4 p = *(const float4*)&Wp[d * 256 + jg * 4];
    acc.x += s * p.x; acc.y += s * p.y; acc.z += s * p.z; acc.w += s * p.w;
  }
  *(float4*)&Wvp[(size_t)i * 256 + jg * 4] = acc;
  float pb = 0.f;
#pragma unroll
  for (int u = 0; u < 8; ++u) { const int d = jg * 8 + u; pb += wrow[d] * bp[d]; }
#pragma unroll
  for (int m = 1; m <= 32; m <<= 1) pb += __shfl_xor(pb, m);
  if (jg == 0) bvp[i] = pb + bv[i];
}

// Packed-B layout (harness-verified rounds 4/7-14), N x K row-major source:
//   B[n][k] -> Bp[(((n>>4)*(K/32) + (k>>5))*64 + ((k>>3)&3)*16 + (n&15))*8 + (k&7)]
__global__ __launch_bounds__(256) void prep_wc_cast(
    const float* __restrict__ Wo, const float* __restrict__ bo,
    const float* __restrict__ Wvp, const float* __restrict__ bvp,
    bf16_t* __restrict__ Wc, float* __restrict__ bcomb,
    const float* __restrict__ W1, const float* __restrict__ W2,
    bf16_t* __restrict__ W1b, bf16_t* __restrict__ W2b) {
  const int b = blockIdx.x;
  const int t = threadIdx.x;
  if (b < 128) {
    const int rs = t >> 6, jg = t & 63;
    const int o = b * 4 + rs;
    const float* worow = Wo + (size_t)o * 512;
    float4 acc = {0.f, 0.f, 0.f, 0.f};
#pragma unroll 4
    for (int i = 0; i < 512; ++i) {
      const float s = worow[i];
      const float4 p = *(const float4*)&Wvp[i * 256 + jg * 4];
      acc.x += s * p.x; acc.y += s * p.y; acc.z += s * p.z; acc.w += s * p.w;
    }
    const int g = o >> 4, rr = o & 15;
    const float av[4] = {acc.x, acc.y, acc.z, acc.w};
#pragma unroll
    for (int u = 0; u < 4; ++u) {
      const int k = jg * 4 + u;
      const int tt = k >> 5, q = (k >> 3) & 3, e = k & 7;
      Wc[((((size_t)g * 8 + tt) * 64) + q * 16 + rr) * 8 + e] = (bf16_t)av[u];  // S=8
    }
    float pb = 0.f;
#pragma unroll
    for (int u = 0; u < 8; ++u) { const int i = jg * 8 + u; pb += worow[i] * bvp[i]; }
#pragma unroll
    for (int m = 1; m <= 32; m <<= 1) pb += __shfl_xor(pb, m);
    if (jg == 0) bcomb[o] = pb + bo[o];
  } else {
    const int idx = ((b - 128) * 256 + t) * 8;
    const float* s;
    bf16_t* d;
    if (idx < 524288) {  // W1: K=512, S=16
      const int o = idx >> 9, k = idx & 511;
      const int g = o >> 4, rr = o & 15, tt = k >> 5, q = (k >> 3) & 3;
      s = W1 + idx;
      d = W1b + ((((size_t)g * 16 + tt) * 64) + q * 16 + rr) * 8;
    } else {             // W2: K=1024, S=32
      const int i2 = idx - 524288;
      const int o = i2 >> 10, k = i2 & 1023;
      const int g = o >> 4, rr = o & 15, tt = k >> 5, q = (k >> 3) & 3;
      s = W2 + i2;
      d = W2b + ((((size_t)g * 32 + tt) * 64) + q * 16 + rr) * 8;
    }
    float4 u0 = *(const float4*)s;
    float4 u1 = *(const float4*)(s + 4);
    bf16x8 v;
    v[0] = (bf16_t)u0.x; v[1] = (bf16_t)u0.y; v[2] = (bf16_t)u0.z; v[3] = (bf16_t)u0.w;
    v[4] = (bf16_t)u1.x; v[5] = (bf16_t)u1.y; v[6] = (bf16_t)u1.z; v[7] = (bf16_t)u1.w;
    *(bf16x8*)d = v;
  }
}

// ---------------- fully fused block kernel ----------------
// ROUND-15: round 14 proved the total-minus-fused gap (~280us) is fixed
// harness overhead -- the fused kernel is the only lever. Its dominant
// reducible term is the per-CU L2 weight stream: 32-row blocks = 8 blocks/CU
// x 2.25MB = 18MB -> ~133us. Round 13's 64-row geometry halves that (9MB)
// but its full-step dbuf (bCur[8]+bNxt[8]=128 regs on acc 128) spilled.
// This round: 64-row geometry + ROUND-8's PROVEN ping-pong kloop
// (bA[H]/bB[H], cross-step prefetch of first half between MFMA halves) --
// measured 96 arch VGPR + 128 acc, zero spill, at this exact wave-tile.
//
// 64-row blocks, 256 thr / 4 waves (wave = col quarter x all 64 rows,
// acc[4][8]); h in 128-col EIGHTHS (lH 16KB); LDS 80KB -> 2 blocks/CU.
// B-bytes/MFMA 512 -> 256; per-CU weight stream 18 -> 9 MB.
//
// Phases: P0 pert->lX | P1 attn K=256 ->LN1-> x->lX | 8x { P2e h_e=gelu(
// x@W1 slice)->lH ; P3e acc3 += h_e@W2 slice } | P4 LN2 -> out.

// A-layout, 64-row tiles: 1KB windows; window = (k>>5)*4 + (row>>4);
// 16B slot = rr*4 + (chunk ^ ((rr>>1)&3)) (verified conflict-free).
__device__ __forceinline__ int alay(int row, int k) {
  const int rr = row & 15;
  const int c = (k >> 3) & 3;
  return ((k >> 5) * 4 + (row >> 4)) * 512 +
         (rr * 4 + (c ^ ((rr >> 1) & 3))) * 8 + (k & 7);
}

// Ping-pong K-loop (round-8 proven): per step, load second B-half, read af,
// MFMA first half, prefetch NEXT step's first B-half, MFMA second half.
template <int STEPS, int NJ>
__device__ __forceinline__ void kloop(const bf16_t* __restrict__ lA_,
                                      const bf16_t* __restrict__ Bp,
                                      int g0, int SB, int soff,
                                      int fRd, int lane,
                                      f32x4 (&acc)[4][NJ]) {
  constexpr int H = NJ / 2;
  auto bfrag = [&](int j, int s) {
    return *(const bf16x8*)(Bp + ((size_t)((g0 + j) * SB + (soff + s)) * 64 + lane) * 8);
  };
  bf16x8 bA[H], bB[H];
#pragma unroll
  for (int j = 0; j < H; ++j) bA[j] = bfrag(j, 0);
#pragma unroll
  for (int s = 0; s < STEPS; ++s) {
#pragma unroll
    for (int j = 0; j < H; ++j) bB[j] = bfrag(H + j, s);
    bf16x8 af[4];
#pragma unroll
    for (int i = 0; i < 4; ++i) af[i] = *(const bf16x8*)&lA_[(s * 4 + i) * 512 + fRd];
    __builtin_amdgcn_s_setprio(1);
#pragma unroll
    for (int j = 0; j < H; ++j)
#pragma unroll
      for (int i = 0; i < 4; ++i)
        acc[i][j] = __builtin_amdgcn_mfma_f32_16x16x32_bf16(af[i], bA[j], acc[i][j], 0, 0, 0);
    __builtin_amdgcn_s_setprio(0);
    if (s + 1 < STEPS) {
#pragma unroll
      for (int j = 0; j < H; ++j) bA[j] = bfrag(j, s + 1);  // cross-step prefetch
    }
    __builtin_amdgcn_s_setprio(1);
#pragma unroll
    for (int j = 0; j < H; ++j)
#pragma unroll
      for (int i = 0; i < 4; ++i)
        acc[i][H + j] = __builtin_amdgcn_mfma_f32_16x16x32_bf16(af[i], bB[j], acc[i][H + j], 0, 0, 0);
    __builtin_amdgcn_s_setprio(0);
  }
}

__global__ __launch_bounds__(256, 2) void fused_block(
    const float* __restrict__ pert, const bf16_t* __restrict__ Wc,
    const float* __restrict__ bcomb, const float* __restrict__ cell,
    const float* __restrict__ g1, const float* __restrict__ be1,
    const bf16_t* __restrict__ W1b, const float* __restrict__ b1,
    const bf16_t* __restrict__ W2b, const float* __restrict__ b2,
    const float* __restrict__ g2, const float* __restrict__ be2,
    float* __restrict__ out) {

  __shared__ __align__(16) bf16_t lX[64 * 512];   // 64 KB: pert (K<256), then x
  __shared__ __align__(16) bf16_t lH[64 * 128];   // 16 KB: h eighths
  // LN scratch aliased into lH (h dead at both LN points; pert lives in lX)
  float* rsP = (float*)lH;          // rs[4][64]  = 1 KB
  float* ssP = (float*)lH + 256;    // rss[4][64] = 1 KB

  const int t = threadIdx.x;
  const int m0 = blockIdx.x * 64;
  const int lane = t & 63;
  const int wc = t >> 6;          // wave 0..3 = col quarter; all 64 rows
  const int r = lane & 15;
  const int q = lane >> 4;
  const int qs = q ^ ((r >> 1) & 3);
  const int fRd = r * 32 + qs * 8;

  // ---- P0: stage pert (64 x 256 fp32 -> bf16, A-layout) into lX ----
#pragma unroll
  for (int u = 0; u < 8; ++u) {
    const int g = u * 256 + t;      // slot 0..2047
    const int row = g >> 5;
    const int c = g & 31;
    const float* src = pert + (size_t)(m0 + row) * 256 + c * 8;
    float4 u0 = *(const float4*)src;
    float4 u1 = *(const float4*)(src + 4);
    bf16x8 v;
    v[0] = (bf16_t)u0.x; v[1] = (bf16_t)u0.y; v[2] = (bf16_t)u0.z; v[3] = (bf16_t)u0.w;
    v[4] = (bf16_t)u1.x; v[5] = (bf16_t)u1.y; v[6] = (bf16_t)u1.z; v[7] = (bf16_t)u1.w;
    *(bf16x8*)&lX[alay(row, c * 8)] = v;
  }
  __syncthreads();

  // ---- P1: attn GEMM (K=256), wave cols [128wc,+128) ----
  {
    f32x4 acc1[4][8];
#pragma unroll
    for (int i = 0; i < 4; ++i)
#pragma unroll
      for (int j = 0; j < 8; ++j)
#pragma unroll
        for (int p = 0; p < 4; ++p) acc1[i][j][p] = 0.f;
    kloop<8, 8>(lX, Wc, 8 * wc, 8, 0, fRd, lane, acc1);

    float s_[4][4], ss_[4][4];
#pragma unroll
    for (int i = 0; i < 4; ++i)
#pragma unroll
      for (int p = 0; p < 4; ++p) { s_[i][p] = 0.f; ss_[i][p] = 0.f; }
    float bb[8];
#pragma unroll
    for (int j = 0; j < 8; ++j) bb[j] = bcomb[128 * wc + 16 * j + r];
#pragma unroll
    for (int i = 0; i < 4; ++i)
#pragma unroll
      for (int p = 0; p < 4; ++p) {
        const int rowl = 16 * i + 4 * q + p;
#pragma unroll
        for (int j = 0; j < 8; ++j) {
          const int col = 128 * wc + 16 * j + r;
          float v = acc1[i][j][p] + bb[j] + cell[(size_t)(m0 + rowl) * 512 + col];
          acc1[i][j][p] = v;
          s_[i][p] += v;
          ss_[i][p] += v * v;
        }
      }
#pragma unroll
    for (int m = 1; m <= 8; m <<= 1)
#pragma unroll
      for (int i = 0; i < 4; ++i)
#pragma unroll
        for (int p = 0; p < 4; ++p) {
          s_[i][p] += __shfl_xor(s_[i][p], m);
          ss_[i][p] += __shfl_xor(ss_[i][p], m);
        }
    __syncthreads();  // all waves past kloop before scratch write / x overwrite
    if (r == 0) {
#pragma unroll
      for (int i = 0; i < 4; ++i)
#pragma unroll
        for (int p = 0; p < 4; ++p) {
          const int rowl = 16 * i + 4 * q + p;
          rsP[wc * 64 + rowl] = s_[i][p];
          ssP[wc * 64 + rowl] = ss_[i][p];
        }
    }
    __syncthreads();
    float mu[4][4], inv[4][4];
#pragma unroll
    for (int i = 0; i < 4; ++i)
#pragma unroll
      for (int p = 0; p < 4; ++p) {
        const int rowl = 16 * i + 4 * q + p;
        float tS = rsP[rowl] + rsP[64 + rowl] + rsP[128 + rowl] + rsP[192 + rowl];
        float tQ = ssP[rowl] + ssP[64 + rowl] + ssP[128 + rowl] + ssP[192 + rowl];
        float m_ = tS * (1.0f / 512.0f);
        float v_ = tQ * (1.0f / 512.0f) - m_ * m_;
        mu[i][p] = m_;
        inv[i][p] = rsqrtf(v_ + 1e-5f);
      }
    float ga[8], be[8];
#pragma unroll
    for (int j = 0; j < 8; ++j) {
      ga[j] = g1[128 * wc + 16 * j + r];
      be[j] = be1[128 * wc + 16 * j + r];
    }
#pragma unroll
    for (int i = 0; i < 4; ++i)
#pragma unroll
      for (int p = 0; p < 4; ++p) {
        const int rowl = 16 * i + 4 * q + p;
#pragma unroll
        for (int j = 0; j < 8; ++j) {
          const int col = 128 * wc + 16 * j + r;
          float v = (acc1[i][j][p] - mu[i][p]) * inv[i][p] * ga[j] + be[j];
          lX[alay(rowl, col)] = (bf16_t)v;
        }
      }
  }
  __syncthreads();  // x fully resident (pert dead)

  // ---- FFN: eight 128-col h-eighths ----
  f32x4 acc3[4][8];
#pragma unroll
  for (int i = 0; i < 4; ++i)
#pragma unroll
    for (int j = 0; j < 8; ++j)
#pragma unroll
      for (int p = 0; p < 4; ++p) acc3[i][j][p] = 0.f;

  for (int e = 0; e < 8; ++e) {
    {
      f32x4 accq[4][2];
#pragma unroll
      for (int i = 0; i < 4; ++i)
#pragma unroll
        for (int j = 0; j < 2; ++j)
#pragma unroll
          for (int p = 0; p < 4; ++p) accq[i][j][p] = 0.f;
      // P2e: h_e = x @ W1[128e : +128]^T  (K=512; wave cols [32wc,+32))
      kloop<16, 2>(lX, W1b, 8 * e + 2 * wc, 16, 0, fRd, lane, accq);
      float bb1[2];
#pragma unroll
      for (int j = 0; j < 2; ++j) bb1[j] = b1[128 * e + 32 * wc + 16 * j + r];
#pragma unroll
      for (int i = 0; i < 4; ++i)
#pragma unroll
        for (int p = 0; p < 4; ++p) {
          const int rowl = 16 * i + 4 * q + p;
#pragma unroll
          for (int j = 0; j < 2; ++j) {
            const int col = 32 * wc + 16 * j + r;   // local col in eighth
            float v = accq[i][j][p] + bb1[j];
            float g = 0.5f * v * (1.0f + erff(v * 0.70710678118654752f));
            lH[alay(rowl, col)] = (bf16_t)g;
          }
        }
    }
    __syncthreads();  // h_e resident everywhere
    // P3e: acc3 += h_e @ W2[:, 128e : +128]^T  (K=128 -> steps 4e..4e+3)
    kloop<4, 8>(lH, W2b, 8 * wc, 32, 4 * e, fRd, lane, acc3);
    __syncthreads();  // all reads of h_e done before overwrite
  }

  // ---- P4: LN2(acc3 + b2 + x) -> fp32 out ----
  {
    float s_[4][4], ss_[4][4];
#pragma unroll
    for (int i = 0; i < 4; ++i)
#pragma unroll
      for (int p = 0; p < 4; ++p) { s_[i][p] = 0.f; ss_[i][p] = 0.f; }
    float bb2[8];
#pragma unroll
    for (int j = 0; j < 8; ++j) bb2[j] = b2[128 * wc + 16 * j + r];
#pragma unroll
    for (int i = 0; i < 4; ++i)
#pragma unroll
      for (int p = 0; p < 4; ++p) {
        const int rowl = 16 * i + 4 * q + p;
#pragma unroll
        for (int j = 0; j < 8; ++j) {
          const int col = 128 * wc + 16 * j + r;
          float v = acc3[i][j][p] + bb2[j] + (float)lX[alay(rowl, col)];
          acc3[i][j][p] = v;
          s_[i][p] += v;
          ss_[i][p] += v * v;
        }
      }
#pragma unroll
    for (int m = 1; m <= 8; m <<= 1)
#pragma unroll
      for (int i = 0; i < 4; ++i)
#pragma unroll
        for (int p = 0; p < 4; ++p) {
          s_[i][p] += __shfl_xor(s_[i][p], m);
          ss_[i][p] += __shfl_xor(ss_[i][p], m);
        }
    // lH readers (P3 e=7) done at loop-end barrier; scratch write safe
    if (r == 0) {
#pragma unroll
      for (int i = 0; i < 4; ++i)
#pragma unroll
        for (int p = 0; p < 4; ++p) {
          const int rowl = 16 * i + 4 * q + p;
          rsP[wc * 64 + rowl] = s_[i][p];
          ssP[wc * 64 + rowl] = ss_[i][p];
        }
    }
    __syncthreads();
    float mu[4][4], inv[4][4];
#pragma unroll
    for (int i = 0; i < 4; ++i)
#pragma unroll
      for (int p = 0; p < 4; ++p) {
        const int rowl = 16 * i + 4 * q + p;
        float tS = rsP[rowl] + rsP[64 + rowl] + rsP[128 + rowl] + rsP[192 + rowl];
        float tQ = ssP[rowl] + ssP[64 + rowl] + ssP[128 + rowl] + ssP[192 + rowl];
        float m_ = tS * (1.0f / 512.0f);
        float v_ = tQ * (1.0f / 512.0f) - m_ * m_;
        mu[i][p] = m_;
        inv[i][p] = rsqrtf(v_ + 1e-5f);
      }
    float ga[8], be[8];
#pragma unroll
    for (int j = 0; j < 8; ++j) {
      ga[j] = g2[128 * wc + 16 * j + r];
      be[j] = be2[128 * wc + 16 * j + r];
    }
#pragma unroll
    for (int i = 0; i < 4; ++i)
#pragma unroll
      for (int p = 0; p < 4; ++p) {
        const int rowl = 16 * i + 4 * q + p;
#pragma unroll
        for (int j = 0; j < 8; ++j) {
          const int col = 128 * wc + 16 * j + r;
          out[(size_t)(m0 + rowl) * 512 + col] =
              (acc3[i][j][p] - mu[i][p]) * inv[i][p] * ga[j] + be[j];
        }
      }
  }
}

extern "C" void kernel_launch(void* const* d_in, const int* in_sizes, int n_in,
                              void* d_out, int out_size, void* d_ws, size_t ws_size,
                              hipStream_t stream) {
  const float* cell = (const float*)d_in[0];
  const float* pert = (const float*)d_in[1];
  const float* Wp   = (const float*)d_in[2];
  const float* bp   = (const float*)d_in[3];
  // d_in[4..7] = Wq,bq,Wk,bk: dead (softmax over a single key == 1 -> attn = v)
  const float* Wv   = (const float*)d_in[8];
  const float* bv   = (const float*)d_in[9];
  const float* Wo   = (const float*)d_in[10];
  const float* bo   = (const float*)d_in[11];
  const float* g1   = (const float*)d_in[12];
  const float* be1  = (const float*)d_in[13];
  const float* g2   = (const float*)d_in[14];
  const float* be2  = (const float*)d_in[15];
  const float* W1   = (const float*)d_in[16];
  const float* b1   = (const float*)d_in[17];
  const float* W2   = (const float*)d_in[18];
  const float* b2   = (const float*)d_in[19];

  char* ws = (char*)d_ws;
  float*  Wvp   = (float*)(ws + 0);          // 512*256*4   = 524288
  float*  bvp   = (float*)(ws + 524288);     // 512*4 (pad) = 2048
  float*  bcomb = (float*)(ws + 526336);     // 512*4 (pad) = 2048
  bf16_t* Wc    = (bf16_t*)(ws + 528384);    // 512*256*2   = 262144 (packed)
  bf16_t* W1b   = (bf16_t*)(ws + 790528);    // 1024*512*2  = 1048576 (packed)
  bf16_t* W2b   = (bf16_t*)(ws + 1839104);   // 512*1024*2  = 1048576 (packed)
  (void)in_sizes; (void)n_in; (void)out_size; (void)ws_size;

  prep_wvp_fast<<<128, 256, 0, stream>>>(Wv, Wp, bp, bv, Wvp, bvp);
  prep_wc_cast<<<640, 256, 0, stream>>>(Wo, bo, Wvp, bvp, Wc, bcomb,
                                        W1, W2, W1b, W2b);

  fused_block<<<1024, 256, 0, stream>>>(pert, Wc, bcomb, cell, g1, be1,
                                        W1b, b1, W2b, b2, g2, be2,
                                        (float*)d_out);
}